// Round 4
// baseline (183.250 us; speedup 1.0000x reference)
//
#include <hip/hip_runtime.h>
#include <stdint.h>

typedef __attribute__((ext_vector_type(8))) short short8;   // 8 bf16 (4 VGPRs) MFMA operand
typedef __attribute__((ext_vector_type(4))) float floatx4;  // MFMA accumulator

#define NPTS 256   // points per group
#define DIM  256   // feature dim
#define TILE 128   // output tile per block

// round-to-nearest-even fp32 -> bf16, result as bits<<16 (value = bit_cast<float>)
static __device__ __forceinline__ uint32_t rne_hi(float f) {
    uint32_t u = __builtin_bit_cast(uint32_t, f);
    u += 0x7FFFu + ((u >> 16) & 1u);
    return u & 0xFFFF0000u;
}
static __device__ __forceinline__ float hval(uint32_t h) {
    return __builtin_bit_cast(float, h);
}

// ---------------------------------------------------------------------------
// Single fused kernel, no staging LDS, no K-loop barriers.
// grid = (10, G): t 0..3 = XY (w=+1), 4..6 = XX upper-tri (w=-0.5/-1/-0.5,
// off-diag tile double-counted via w), 7..9 = YY upper-tri.
// Each lane loads its MFMA fragments straight from global fp32 (32 contiguous
// bytes per fragment), converts RNE->bf16 in-register, accumulates fragment
// squared-sums for the row/col norms, MFMAs the Gram tile, then fuses the
// distance epilogue sqrt(max(x2+y2-2S,0)) (diag zeroed for XX/YY), reduces,
// and does one atomicAdd per block.
// Norms come from exactly the values the MFMA consumed -> consistent metric.
// ---------------------------------------------------------------------------
__global__ __launch_bounds__(256)
void mmd_one(const float* __restrict__ X, const float* __restrict__ Y,
             float* __restrict__ out, float scale) {
    const int g = blockIdx.y;
    const int t = blockIdx.x;

    int ptype, ti, tj; float w;
    if (t < 4)      { ptype = 0; ti = t >> 1; tj = t & 1; w = 1.0f; }
    else if (t < 7) { int u = t - 4; ptype = 1; ti = (u == 2); tj = (u >= 1); w = (u == 1) ? -1.0f : -0.5f; }
    else            { int u = t - 7; ptype = 2; ti = (u == 2); tj = (u >= 1); w = (u == 1) ? -1.0f : -0.5f; }

    const float *Pf, *Qf;
    if (ptype == 0)      { Pf = X; Qf = Y; }
    else if (ptype == 1) { Pf = X; Qf = X; }
    else                 { Pf = Y; Qf = Y; }
    const bool symdiag = (ptype != 0) && (ti == tj);

    const int tid  = threadIdx.x;
    const int lane = tid & 63;
    const int wv   = tid >> 6;
    const int wrow = (wv >> 1) * 64;     // this wave's 64-row stripe of the 128-tile
    const int wcol = (wv & 1) * 64;
    const int quad = lane >> 4;
    const int l15  = lane & 15;

    // per-lane row base pointers (A-frag rows / B-frag rows), offset by this
    // lane's k-slice (quad*8 elems). Contiguous 32 B per lane per fragment.
    const float* pa[4];
    const float* pb[4];
    #pragma unroll
    for (int mi = 0; mi < 4; ++mi)
        pa[mi] = Pf + ((size_t)g * NPTS + (size_t)ti * TILE + wrow + mi * 16 + l15) * DIM + quad * 8;
    #pragma unroll
    for (int ni = 0; ni < 4; ++ni)
        pb[ni] = Qf + ((size_t)g * NPTS + (size_t)tj * TILE + wcol + ni * 16 + l15) * DIM + quad * 8;

    floatx4 acc[4][4];
    #pragma unroll
    for (int i = 0; i < 4; ++i)
        #pragma unroll
        for (int j = 0; j < 4; ++j) acc[i][j] = (floatx4)0.0f;

    float sqa[4] = {0.f, 0.f, 0.f, 0.f};   // partial ||row||^2 of rounded values
    float sqb[4] = {0.f, 0.f, 0.f, 0.f};   // partial ||col||^2

    #pragma unroll
    for (int it = 0; it < DIM / 32; ++it) {
        const int k0 = it * 32;
        short8 af[4], bfr[4];

        #pragma unroll
        for (int mi = 0; mi < 4; ++mi) {
            const float4 u = *(const float4*)(pa[mi] + k0);
            const float4 v = *(const float4*)(pa[mi] + k0 + 4);
            uint32_t h0 = rne_hi(u.x), h1 = rne_hi(u.y), h2 = rne_hi(u.z), h3 = rne_hi(u.w);
            uint32_t h4 = rne_hi(v.x), h5 = rne_hi(v.y), h6 = rne_hi(v.z), h7 = rne_hi(v.w);
            sqa[mi] += hval(h0) * hval(h0) + hval(h1) * hval(h1)
                     + hval(h2) * hval(h2) + hval(h3) * hval(h3)
                     + hval(h4) * hval(h4) + hval(h5) * hval(h5)
                     + hval(h6) * hval(h6) + hval(h7) * hval(h7);
            const uint4 pk = { (h0 >> 16) | h1, (h2 >> 16) | h3,
                               (h4 >> 16) | h5, (h6 >> 16) | h7 };
            af[mi] = __builtin_bit_cast(short8, pk);
        }
        #pragma unroll
        for (int ni = 0; ni < 4; ++ni) {
            const float4 u = *(const float4*)(pb[ni] + k0);
            const float4 v = *(const float4*)(pb[ni] + k0 + 4);
            uint32_t h0 = rne_hi(u.x), h1 = rne_hi(u.y), h2 = rne_hi(u.z), h3 = rne_hi(u.w);
            uint32_t h4 = rne_hi(v.x), h5 = rne_hi(v.y), h6 = rne_hi(v.z), h7 = rne_hi(v.w);
            sqb[ni] += hval(h0) * hval(h0) + hval(h1) * hval(h1)
                     + hval(h2) * hval(h2) + hval(h3) * hval(h3)
                     + hval(h4) * hval(h4) + hval(h5) * hval(h5)
                     + hval(h6) * hval(h6) + hval(h7) * hval(h7);
            const uint4 pk = { (h0 >> 16) | h1, (h2 >> 16) | h3,
                               (h4 >> 16) | h5, (h6 >> 16) | h7 };
            bfr[ni] = __builtin_bit_cast(short8, pk);
        }

        #pragma unroll
        for (int mi = 0; mi < 4; ++mi)
            #pragma unroll
            for (int ni = 0; ni < 4; ++ni)
                acc[mi][ni] = __builtin_amdgcn_mfma_f32_16x16x32_bf16(
                    af[mi], bfr[ni], acc[mi][ni], 0, 0, 0);
    }

    // quad-butterfly: every lane ends with the FULL norm for its l15 row/col.
    // (lane (quad,l15) held the k-slice [*, quad*8+..] partial of row l15;
    //  xor 16 and xor 32 combine the 4 quads.)
    #pragma unroll
    for (int i = 0; i < 4; ++i) {
        sqa[i] += __shfl_xor(sqa[i], 16); sqa[i] += __shfl_xor(sqa[i], 32);
        sqb[i] += __shfl_xor(sqb[i], 16); sqb[i] += __shfl_xor(sqb[i], 32);
    }

    // fused epilogue. C/D layout: col = lane&15, row = (lane>>4)*4 + reg.
    // cnorm for col wcol+ni*16+l15 is this lane's own sqb[ni]; rnorm for row
    // quad*4+i lives in lane quad*4+i (any quad) -> one shfl.
    float lsum = 0.0f;
    #pragma unroll
    for (int mi = 0; mi < 4; ++mi) {
        #pragma unroll
        for (int i = 0; i < 4; ++i) {
            const int r = wrow + mi * 16 + quad * 4 + i;
            const float rv = __shfl(sqa[mi], quad * 4 + i);
            #pragma unroll
            for (int ni = 0; ni < 4; ++ni) {
                const int c = wcol + ni * 16 + l15;
                float d2 = rv + sqb[ni] - 2.0f * acc[mi][ni][i];
                float s = sqrtf(fmaxf(d2, 0.0f));
                if (symdiag && (r == c)) s = 0.0f;
                lsum += s;
            }
        }
    }
    #pragma unroll
    for (int off = 32; off; off >>= 1) lsum += __shfl_down(lsum, off);

    __shared__ float wpart[4];
    if (lane == 0) wpart[wv] = lsum;
    __syncthreads();
    if (tid == 0) {
        const float bs = wpart[0] + wpart[1] + wpart[2] + wpart[3];
        atomicAdd(out, bs * (w * scale));
    }
}

// ---------------------------------------------------------------------------
extern "C" void kernel_launch(void* const* d_in, const int* in_sizes, int n_in,
                              void* d_out, int out_size, void* d_ws, size_t ws_size,
                              hipStream_t stream) {
    const float* X = (const float*)d_in[0];
    const float* Y = (const float*)d_in[1];
    const int total_elems = in_sizes[0];          // G*NPTS*DIM
    const int G = total_elems / (NPTS * DIM);     // 128

    float* out = (float*)d_out;
    hipMemsetAsync(out, 0, sizeof(float) * out_size, stream);

    const float scale = 1.0f / ((float)NPTS * (float)NPTS * (float)G);
    dim3 grid(10, G);
    mmd_one<<<grid, 256, 0, stream>>>(X, Y, out, scale);
}

// Round 5
// 120.549 us; speedup vs baseline: 1.5201x; 1.5201x over previous
//
#include <hip/hip_runtime.h>
#include <hip/hip_bf16.h>
#include <stdint.h>
#include <string.h>

typedef __attribute__((ext_vector_type(8))) short short8;   // 8 bf16 (4 VGPRs) MFMA operand
typedef __attribute__((ext_vector_type(4))) float floatx4;  // MFMA accumulator

#define NPTS 256   // points per group
#define DIM  256   // feature dim
#define TILE 128   // output tile per block
#define BK   32    // K-step
#define NIT  (DIM / BK)          // 8 K-iterations
#define LDSS 40    // LDS row stride in bf16 elems (80 B: 16B-aligned, banks spread)

// HW packed fp32->bf16 RNE convert (v_cvt_pk_bf16_f32 on gfx950); also
// accumulates the squared sum of the ROUNDED values (consistent metric).
static __device__ __forceinline__ uint32_t cvtsq2(float a, float b, float& s) {
    __hip_bfloat162 h = __float22bfloat162_rn(float2{a, b});
    uint32_t d;
    memcpy(&d, &h, 4);
    const float lo = __builtin_bit_cast(float, d << 16);
    const float hi = __builtin_bit_cast(float, d & 0xFFFF0000u);
    s += lo * lo + hi * hi;
    return d;
}
static __device__ __forceinline__ uint4 cvt8(const float4 u, const float4 v, float& s) {
    uint4 r;
    r.x = cvtsq2(u.x, u.y, s); r.y = cvtsq2(u.z, u.w, s);
    r.z = cvtsq2(v.x, v.y, s); r.w = cvtsq2(v.z, v.w, s);
    return r;
}

// ---------------------------------------------------------------------------
// grid = 10*G linear blocks, XCD-swizzled so all 10 tiles of a group share an
// XCD (L2 reuse). t 0..3 = XY (w=+1), 4..6 = XX upper-tri (w=-0.5/-1/-0.5,
// off-diag tile double-counted via w), 7..9 = YY upper-tri.
// ---------------------------------------------------------------------------
__global__ __launch_bounds__(512, 4)
void mmd_pipe(const float* __restrict__ X, const float* __restrict__ Y,
              float* __restrict__ out, float scale, int G) {
    // ---- block -> (group, tile) decode with XCD swizzle ----
    int g, t;
    const int f = blockIdx.x;
    if ((G & 7) == 0) { const int xcd = f & 7, j = f >> 3; g = (j / 10) * 8 + xcd; t = j % 10; }
    else              { g = f / 10; t = f % 10; }

    int ptype, ti, tj; float w;
    if (t < 4)      { ptype = 0; ti = t >> 1; tj = t & 1; w = 1.0f; }
    else if (t < 7) { int u = t - 4; ptype = 1; ti = (u == 2); tj = (u >= 1); w = (u == 1) ? -1.0f : -0.5f; }
    else            { int u = t - 7; ptype = 2; ti = (u == 2); tj = (u >= 1); w = (u == 1) ? -1.0f : -0.5f; }

    const float *Pf, *Qf;
    if (ptype == 0)      { Pf = X; Qf = Y; }
    else if (ptype == 1) { Pf = X; Qf = X; }
    else                 { Pf = Y; Qf = Y; }
    const bool symdiag = (ptype != 0) && (ti == tj);

    const size_t prow0 = (size_t)g * NPTS + (size_t)ti * TILE;
    const size_t qrow0 = (size_t)g * NPTS + (size_t)tj * TILE;

    __shared__ __align__(16) uint16_t As[2][TILE * LDSS];  // 2 x 10 KB
    __shared__ __align__(16) uint16_t Bs[2][TILE * LDSS];
    __shared__ float rnorm[TILE];
    __shared__ float cnorm[TILE];
    __shared__ float wpart[8];

    const int tid  = threadIdx.x;          // 0..511
    const int lane = tid & 63;
    const int wv   = tid >> 6;             // 0..7
    const int quad = lane >> 4;
    const int l15  = lane & 15;
    const int rowbase = (wv & 3) * 32;     // wave's 32-row stripe
    const int colbase = (wv >> 2) * 64;    // wave's 64-col stripe

    // ---- producer geometry: thread t stages row t>>2, float cols (t&3)*8..+8
    const int prow = tid >> 2;
    const int pcol = (tid & 3) * 8;
    const float* gA = Pf + (prow0 + prow) * DIM + pcol;
    const float* gB = Qf + (qrow0 + prow) * DIM + pcol;
    const int woff = prow * LDSS + pcol;   // bf16-elem offset in LDS slice

    floatx4 acc[2][4];
    #pragma unroll
    for (int i = 0; i < 2; ++i)
        #pragma unroll
        for (int j = 0; j < 4; ++j) acc[i][j] = (floatx4)0.0f;

    float sqp = 0.0f, sqq = 0.0f;          // this thread's partial row norms

    // ---- prologue: slice 0 -> LDS[0]; start loading slice 1 ----
    float4 ra0 = *(const float4*)(gA);
    float4 ra1 = *(const float4*)(gA + 4);
    float4 rb0 = *(const float4*)(gB);
    float4 rb1 = *(const float4*)(gB + 4);
    {
        const uint4 pa = cvt8(ra0, ra1, sqp);
        const uint4 pb = cvt8(rb0, rb1, sqq);
        *(uint4*)&As[0][woff] = pa;
        *(uint4*)&Bs[0][woff] = pb;
    }
    ra0 = *(const float4*)(gA + BK);
    ra1 = *(const float4*)(gA + BK + 4);
    rb0 = *(const float4*)(gB + BK);
    rb1 = *(const float4*)(gB + BK + 4);

    // ---- main pipeline: 1 barrier per iteration, write-ahead-1, load-ahead-2
    #pragma unroll
    for (int it = 0; it < NIT; ++it) {
        const int b = it & 1;
        __syncthreads();                    // LDS[b] (written last iter) visible

        if (it < NIT - 1) {                 // write slice it+1 into LDS[b^1]
            const uint4 pa = cvt8(ra0, ra1, sqp);
            const uint4 pb = cvt8(rb0, rb1, sqq);
            *(uint4*)&As[b ^ 1][woff] = pa;
            *(uint4*)&Bs[b ^ 1][woff] = pb;
        }
        if (it < NIT - 2) {                 // start loading slice it+2
            const int k0 = (it + 2) * BK;
            ra0 = *(const float4*)(gA + k0);
            ra1 = *(const float4*)(gA + k0 + 4);
            rb0 = *(const float4*)(gB + k0);
            rb1 = *(const float4*)(gB + k0 + 4);
        }

        // consume slice it from LDS[b]
        short8 af[2], bfr[4];
        #pragma unroll
        for (int mi = 0; mi < 2; ++mi)
            af[mi] = *(const short8*)&As[b][(rowbase + mi * 16 + l15) * LDSS + quad * 8];
        #pragma unroll
        for (int ni = 0; ni < 4; ++ni)
            bfr[ni] = *(const short8*)&Bs[b][(colbase + ni * 16 + l15) * LDSS + quad * 8];
        #pragma unroll
        for (int mi = 0; mi < 2; ++mi)
            #pragma unroll
            for (int ni = 0; ni < 4; ++ni)
                acc[mi][ni] = __builtin_amdgcn_mfma_f32_16x16x32_bf16(
                    af[mi], bfr[ni], acc[mi][ni], 0, 0, 0);
    }

    // ---- assemble row/col norms: reduce over the 4 staging threads per row
    sqp += __shfl_xor(sqp, 1); sqp += __shfl_xor(sqp, 2);
    sqq += __shfl_xor(sqq, 1); sqq += __shfl_xor(sqq, 2);
    if ((tid & 3) == 0) { rnorm[prow] = sqp; cnorm[prow] = sqq; }
    __syncthreads();

    // ---- fused epilogue: d = sqrt(max(x2_i + y2_j - 2 S_ij, 0)) ----
    // C/D layout: col = lane&15, row = (lane>>4)*4 + reg.
    float lsum = 0.0f;
    #pragma unroll
    for (int mi = 0; mi < 2; ++mi) {
        #pragma unroll
        for (int i = 0; i < 4; ++i) {
            const int r = rowbase + mi * 16 + quad * 4 + i;
            const float rv = rnorm[r];
            #pragma unroll
            for (int ni = 0; ni < 4; ++ni) {
                const int c = colbase + ni * 16 + l15;
                float d2 = rv + cnorm[c] - 2.0f * acc[mi][ni][i];
                float s = sqrtf(fmaxf(d2, 0.0f));
                if (symdiag && (r == c)) s = 0.0f;
                lsum += s;
            }
        }
    }
    #pragma unroll
    for (int off = 32; off; off >>= 1) lsum += __shfl_down(lsum, off);
    if (lane == 0) wpart[wv] = lsum;
    __syncthreads();
    if (tid == 0) {
        float bs = 0.0f;
        #pragma unroll
        for (int i = 0; i < 8; ++i) bs += wpart[i];
        atomicAdd(out, bs * (w * scale));
    }
}

// ---------------------------------------------------------------------------
extern "C" void kernel_launch(void* const* d_in, const int* in_sizes, int n_in,
                              void* d_out, int out_size, void* d_ws, size_t ws_size,
                              hipStream_t stream) {
    const float* X = (const float*)d_in[0];
    const float* Y = (const float*)d_in[1];
    const int total_elems = in_sizes[0];          // G*NPTS*DIM
    const int G = total_elems / (NPTS * DIM);     // 128

    float* out = (float*)d_out;
    hipMemsetAsync(out, 0, sizeof(float) * out_size, stream);

    const float scale = 1.0f / ((float)NPTS * (float)NPTS * (float)G);
    mmd_pipe<<<10 * G, 512, 0, stream>>>(X, Y, out, scale, G);
}